// Round 20
// baseline (481.387 us; speedup 1.0000x reference)
//
#include <hip/hip_runtime.h>

// VectorQuantizer: fp8-MFMA approximate distance pass + margin shortlist +
// exact f32 rescore + gather/losses.  N=32768, D=256, K=8192.
//
// R20 = R18 (321us, proven envelope: 512thr, 16 waves/CU, fragment-major,
// 0 conflicts, post-barrier epilogue) with the approx pass moved to
// mfma_f32_16x16x32_fp8_fp8: same FLOP rate as bf16 (guide), but 512B
// fragments -> per-CU-chunk LDS 2560 -> 1280 cyc. Bs 2x16KB, VGPR ~56 --
// stays inside the (LDS<=64KB, VGPR<=64) 2-blk envelope that R16/R19
// proved is worth more than any LDS-BW trade that breaks it.
// Numerics: emb pre-scaled by 2^13 (exact; e_scaled in +-0.98 e4m3 sweet
// spot), z direct. sigma(eps_d) ~ 5.7e-5, 6-sigma ~ 3.4e-4 ->
// MARGIN 1e-3 (3x headroom), CAP 128 (mean appends ~16, list 16MB).
// Epilogue: d = fmaf(-2^-12, acc, a) + c (exact pow2 fold). Rescore's
// exact f32 chain + superset logic unchanged (R5-verified).

#define NROWS 32768
#define NE    8192
#define DDIM  256
#define BM    64
#define CAP   128
#define MARGIN 1e-3f
#define NCH   (NE / 64)    // 128 chunks of 64 candidates
#define ESCALE 8192.0f     // 2^13
#define DSCALE (1.0f/4096.0f)   // 2^-12 = 2 * 2^-13
#define USCALE 4096.0f          // 2^12

typedef __attribute__((ext_vector_type(4))) float f32x4;
typedef unsigned long long u64;

__device__ __forceinline__ u64 pack_fp8x8(float4 v0, float4 v1, float s) {
  int w0 = 0, w1 = 0;
  w0 = __builtin_amdgcn_cvt_pk_fp8_f32(v0.x * s, v0.y * s, w0, false);
  w0 = __builtin_amdgcn_cvt_pk_fp8_f32(v0.z * s, v0.w * s, w0, true);
  w1 = __builtin_amdgcn_cvt_pk_fp8_f32(v1.x * s, v1.y * s, w1, false);
  w1 = __builtin_amdgcn_cvt_pk_fp8_f32(v1.z * s, v1.w * s, w1, true);
  return ((u64)(unsigned)w1 << 32) | (unsigned)w0;
}

__device__ __forceinline__ void gload_lds16(const void* g, void* l) {
  __builtin_amdgcn_global_load_lds(
      (const __attribute__((address_space(1))) void*)g,
      (__attribute__((address_space(3))) void*)l, 16, 0, 0);
}

// ---------------- row norms: a[n] = sum z^2, c[k] = sum e^2 -------------
__global__ __launch_bounds__(256)
void vq_norms(const float* __restrict__ z, const float* __restrict__ emb,
              float* __restrict__ arow, float* __restrict__ cemb) {
  int gid  = blockIdx.x * 256 + threadIdx.x;
  int wid  = gid >> 6;
  int lane = threadIdx.x & 63;
  const float* src;
  float* dst;
  if (wid < NROWS) { src = z + (size_t)wid * DDIM;   dst = arow + wid; }
  else             { int r = wid - NROWS;
                     src = emb + (size_t)r * DDIM;   dst = cemb + r; }
  float4 v = *reinterpret_cast<const float4*>(src + lane * 4);
  float s = v.x * v.x + v.y * v.y;
  s += v.z * v.z;
  s += v.w * v.w;
  #pragma unroll
  for (int off = 1; off < 64; off <<= 1) s += __shfl_xor(s, off, 64);
  if (lane == 0) *dst = s;
}

// -------- emb f32 -> fp8 e4m3 (x 2^13), FRAGMENT-MAJOR ------------------
// 8B unit o: frag = o>>6 (512B), lane l = o&63.
// frag: g16 = frag>>3 (16-cand group), s = frag&7 (K=32 step).
// lane holds cand (g16*16 + (l&15)), bytes k = s*32 + (l>>4)*8 .. +8.
// Candidate-chunk ch (64 cands) = g16 in [4ch,4ch+4) = 16KB contiguous.
__global__ __launch_bounds__(256)
void vq_cvt8(const float* __restrict__ emb, u64* __restrict__ e8) {
  int o    = blockIdx.x * 256 + threadIdx.x;   // 0 .. NE*32-1 (8B units)
  int frag = o >> 6;
  int l    = o & 63;
  int g16  = frag >> 3;
  int s    = frag & 7;
  int cand = g16 * 16 + (l & 15);
  int k    = s * 32 + (l >> 4) * 8;
  const float* src = emb + (size_t)cand * DDIM + k;
  float4 v0 = *reinterpret_cast<const float4*>(src);
  float4 v1 = *reinterpret_cast<const float4*>(src + 4);
  e8[o] = pack_fp8x8(v0, v1, ESCALE);
}

// ---------------- MFMA approx pass + shortlist (fp8) --------------------
// 8 waves: wm=wid>>1 (4 x 16-row group), wn=wid&1 (2 x 32-cand half),
// ci in {0,1}. Swapped operands mfma(cand_frag, zrow_frag):
// D col = z-row (l15), D row = cand (lg*4 + r). Same mapping as R18.
__global__ __launch_bounds__(512, 4)
void vq_mfma(const float* __restrict__ z, const u64* __restrict__ e8,
             const float* __restrict__ arow, const float* __restrict__ cemb,
             unsigned* __restrict__ cnt, int* __restrict__ list) {
  __shared__ char Bs[2][16384];   // 2 x 16 KB, fragment-major fp8

  const int t    = threadIdx.x;
  const int R0   = blockIdx.x * BM;
  const int lane = t & 63;
  const int wid  = t >> 6;          // 0..7
  const int wm   = wid >> 1;        // 0..3 : 16-row group
  const int wn   = wid & 1;         // 0..1 : 32-cand half
  const int l15  = lane & 15;
  const int lg   = lane >> 4;       // 0..3

  // ---- A fragments: z-row -> fp8 in registers (8 K-steps of 32) ----
  // af[s]: 8 bytes = fp8(z[row][s*32 + lg*8 .. +8]), unscaled
  u64 af[8];
  const int row = R0 + wm * 16 + l15;
  {
    const float* zr = z + (size_t)row * DDIM;
    #pragma unroll
    for (int s = 0; s < 8; ++s) {
      const float* src = zr + s * 32 + lg * 8;
      float4 v0 = *reinterpret_cast<const float4*>(src);
      float4 v1 = *reinterpret_cast<const float4*>(src + 4);
      af[s] = pack_fp8x8(v0, v1, 1.0f);
    }
  }
  const float a_r = arow[row];
  float runmin = 3.4e38f;

  // ---- prologue: DMA chunk 0 -> Bs[0] (16KB; wave stages 2x1KB) ----
  {
    const char* src = (const char*)e8;
    #pragma unroll
    for (int i = 0; i < 2; ++i) {
      int f = wid * 2 + i;
      gload_lds16(src + f * 1024 + lane * 16, &Bs[0][0] + f * 1024);
    }
  }
  __syncthreads();   // drains prologue DMA

  for (int ch = 0; ch < NCH; ++ch) {
    const int buf = ch & 1;
    const int C0  = ch * 64;

    // ---- issue next chunk's DMA first (whole chunk to land) ----
    if (ch + 1 < NCH) {
      const char* src = (const char*)e8 + (size_t)(ch + 1) * 16384;
      char* dst = &Bs[buf ^ 1][0];
      #pragma unroll
      for (int i = 0; i < 2; ++i) {
        int f = wid * 2 + i;
        gload_lds16(src + f * 1024 + lane * 16, dst + f * 1024);
      }
    }

    // ---- hoisted epilogue constants (live across barrier in regs) ----
    float4 cvv[2];
    #pragma unroll
    for (int ci = 0; ci < 2; ++ci)
      cvv[ci] = *reinterpret_cast<const float4*>(
          &cemb[C0 + wn * 32 + ci * 16 + lg * 4]);

    // ---- compute: contiguous 512B fragment reads (b64), 16 MFMAs ----
    f32x4 acc[2];
    acc[0] = (f32x4){0.f, 0.f, 0.f, 0.f};
    acc[1] = (f32x4){0.f, 0.f, 0.f, 0.f};

    const char* Bp = &Bs[buf][0];
    #pragma unroll
    for (int s = 0; s < 8; ++s) {
      u64 bfr[2];
      #pragma unroll
      for (int ci = 0; ci < 2; ++ci)
        bfr[ci] = *reinterpret_cast<const u64*>(
            Bp + (((wn * 2 + ci) * 8 + s) * 512) + lane * 8);
      #pragma unroll
      for (int ci = 0; ci < 2; ++ci)
        acc[ci] = __builtin_amdgcn_mfma_f32_16x16x32_fp8_fp8(
            (long)bfr[ci], (long)af[s], acc[ci], 0, 0, 0);
    }

    __syncthreads();   // compute(buf) done by ALL waves; next DMA drained

    // ---- POST-BARRIER epilogue (regs + global only, no LDS) ----
    // d = a - 2^-12*acc + c   (acc = 2^13 * u, fold exact)
    float lm = 3.4e38f;
    #pragma unroll
    for (int ci = 0; ci < 2; ++ci)
      #pragma unroll
      for (int r = 0; r < 4; ++r) {
        float dd = fmaf(-DSCALE, acc[ci][r], a_r) + cvv[ci][r];
        lm = fminf(lm, dd);
      }
    float gm = fminf(lm, __shfl_xor(lm, 16, 64));
    gm = fminf(gm, __shfl_xor(gm, 32, 64));
    runmin = fminf(runmin, gm);
    float thr = runmin + MARGIN;
    if (lm <= thr) {
      // u-form test: d<=thr <=> acc >= 2^12*(a + c - thr)
      const float h = USCALE * (a_r - thr);
      #pragma unroll
      for (int ci = 0; ci < 2; ++ci)
        #pragma unroll
        for (int r = 0; r < 4; ++r)
          if (acc[ci][r] >= fmaf(USCALE, cvv[ci][r], h)) {
            int k = C0 + wn * 32 + ci * 16 + lg * 4 + r;
            unsigned p = atomicAdd(&cnt[row], 1u);
            if (p < CAP) list[(size_t)row * CAP + p] = k;
          }
    }
  }
}

// ---------------- exact f32 rescore of shortlists (R15-verified) --------
__global__ __launch_bounds__(256)
void vq_rescore(const float* __restrict__ z, const float* __restrict__ emb,
                const float* __restrict__ arow, const float* __restrict__ cemb,
                const unsigned* __restrict__ cnt, const int* __restrict__ list,
                int* __restrict__ ws_idx) {
  const int row  = blockIdx.x * 4 + (threadIdx.x >> 6);
  const int lane = threadIdx.x & 63;
  const float a  = arow[row];
  const float4 zv = *reinterpret_cast<const float4*>(
      z + (size_t)row * DDIM + lane * 4);
  unsigned n = cnt[row];
  float bd = 3.4e38f;
  int   bk = 0;

  const bool fullscan = (n == 0 || n > CAP);
  const int  m = fullscan ? NE : (int)n;
  for (int i = 0; i < m; ++i) {
    int k = fullscan ? i : list[(size_t)row * CAP + i];
    const float4 ev = *reinterpret_cast<const float4*>(
        emb + (size_t)k * DDIM + lane * 4);
    float p = zv.x * ev.x;
    p = fmaf(zv.y, ev.y, p);
    p = fmaf(zv.z, ev.z, p);
    p = fmaf(zv.w, ev.w, p);
    #pragma unroll
    for (int off = 1; off < 64; off <<= 1) p += __shfl_xor(p, off, 64);
    float d = fmaf(-2.0f, p, a) + cemb[k];   // exact ref chain
    if (d < bd || (d == bd && k < bk)) { bd = d; bk = k; }
  }
  if (lane == 0) ws_idx[row] = bk;
}

// ---------------- gather + STE + losses (R16-verified, 64 rows/blk) -----
__global__ __launch_bounds__(256)
void vq_gather(const float* __restrict__ z, const float* __restrict__ emb,
               const int* __restrict__ ws_idx,
               float* __restrict__ out_zq, float* __restrict__ out_idx,
               double* __restrict__ loss_accum) {
  __shared__ float part[4];
  const int t  = threadIdx.x;
  const int R0 = blockIdx.x * 64;
  float lsum = 0.0f;
  for (int rr = 0; rr < 64; ++rr) {
    const int kb = ws_idx[R0 + rr];
    const size_t gi = (size_t)(R0 + rr) * DDIM + t;
    const float zv = z[gi];
    const float qv = emb[(size_t)kb * DDIM + t];
    const float diff = qv - zv;              // z_q - z
    out_zq[gi] = zv + diff;                  // z + (z_q - z) exact chain
    lsum = fmaf(diff, diff, lsum);
  }
  #pragma unroll
  for (int off = 1; off < 64; off <<= 1) lsum += __shfl_xor(lsum, off, 64);
  if ((t & 63) == 0) part[t >> 6] = lsum;
  __syncthreads();
  if (t == 0) {
    float tot = (part[0] + part[1]) + (part[2] + part[3]);
    atomicAdd(loss_accum, (double)tot);
  }
  if (t < 64) out_idx[R0 + t] = (float)ws_idx[R0 + t];
}

// ---------------- scalar losses -----------------------------------------
__global__ void vq_finalize(const double* __restrict__ loss_accum,
                            float* __restrict__ out_losses) {
  double m = *loss_accum / (double)((size_t)NROWS * DDIM);
  out_losses[0] = (float)(0.25 * m);   // loss_commit = BETA * mse
  out_losses[1] = (float)m;            // loss_codebook
}

extern "C" void kernel_launch(void* const* d_in, const int* in_sizes, int n_in,
                              void* d_out, int out_size, void* d_ws, size_t ws_size,
                              hipStream_t stream) {
  const float* z   = (const float*)d_in[0];
  const float* emb = (const float*)d_in[1];
  float* out        = (float*)d_out;
  float* out_zq     = out;                            // [8388608]
  float* out_losses = out + (size_t)NROWS * DDIM;     // [2]
  float* out_idx    = out + (size_t)NROWS * DDIM + 2; // [32768] as f32

  // persistent ws scratch (small)
  double* loss_accum = (double*)d_ws;
  float*  arow   = (float*)((char*)d_ws + 256);
  float*  cemb   = arow + NROWS;
  int*    ws_idx = (int*)(cemb + NE);

  // large scratch carved from d_out's z_q region (fully rewritten each call;
  // vq_gather overwrites only after rescore consumed list/cnt => safe)
  u64*      e8   = (u64*)d_out;                              // [0, 2MB)
  int*      list = (int*)((char*)d_out + (2 << 20));         // [2MB, 18MB) CAP=128
  unsigned* cnt  = (unsigned*)((char*)d_out + (18 << 20));   // [18MB, +128KB)

  hipMemsetAsync(d_ws, 0, 8, stream);
  hipMemsetAsync(cnt, 0, NROWS * sizeof(unsigned), stream);
  vq_norms<<<(NROWS + NE) / 4, 256, 0, stream>>>(z, emb, arow, cemb);
  vq_cvt8<<<NE * 32 / 256, 256, 0, stream>>>(emb, e8);
  vq_mfma<<<NROWS / BM, 512, 0, stream>>>(z, e8, arow, cemb, cnt, list);
  vq_rescore<<<NROWS / 4, 256, 0, stream>>>(z, emb, arow, cemb, cnt, list, ws_idx);
  vq_gather<<<NROWS / 64, 256, 0, stream>>>(z, emb, ws_idx,
                                            out_zq, out_idx, loss_accum);
  vq_finalize<<<1, 1, 0, stream>>>(loss_accum, out_losses);
}

// Round 21
// 376.579 us; speedup vs baseline: 1.2783x; 1.2783x over previous
//
#include <hip/hip_runtime.h>

// VectorQuantizer: bf16-MFMA approximate distance pass + margin shortlist +
// exact f32 rescore + gather/losses.  N=32768, D=256, K=8192.
//
// R21 = R18 (321us) + T4 counted-vmcnt pipeline in vq_mfma:
// R18's wall==sum-of-pipes (4556 ~= 2560 LDS + 1030 MFMA + 1120 VALU):
// __syncthreads' vmcnt(0) drains the JUST-ISSUED next-chunk DMA every
// barrier (the m97-structure stall). Fix: chunk 64->32 (16KB buffers),
// THREE buffers (48KB, keeps 2 blk/CU), s_waitcnt vmcnt(2) + raw
// s_barrier -- chunk+1's loads stay in flight across the barrier; DMA
// for a buffer is issued only after the barrier proving all waves
// finished reading it (rotation: read ch%3, write (ch+2)%3, in-flight
// (ch+1)%3). Last iter vmcnt(0). fp8 (R20) abandoned: e4m3 error forces
// MARGIN 1e-3 -> 10x appends -> net loss. Also: gather vectorized to
// float4 (1 wave/row), ~35->20us.

#define NROWS 32768
#define NE    8192
#define DDIM  256
#define BM    64
#define CAP   64
#define MARGIN 1e-4f
#define NCH   (NE / 32)    // 256 chunks of 32 candidates

typedef __attribute__((ext_vector_type(8))) short bf16x8;
typedef __attribute__((ext_vector_type(4))) float f32x4;
typedef unsigned short u16;

__device__ __forceinline__ u16 f2bf(float f) {
  unsigned x = __float_as_uint(f);
  return (u16)((x + 0x7fffu + ((x >> 16) & 1u)) >> 16);   // RNE
}

__device__ __forceinline__ void gload_lds16(const void* g, void* l) {
  __builtin_amdgcn_global_load_lds(
      (const __attribute__((address_space(1))) void*)g,
      (__attribute__((address_space(3))) void*)l, 16, 0, 0);
}

// ---------------- row norms: a[n] = sum z^2, c[k] = sum e^2 -------------
__global__ __launch_bounds__(256)
void vq_norms(const float* __restrict__ z, const float* __restrict__ emb,
              float* __restrict__ arow, float* __restrict__ cemb) {
  int gid  = blockIdx.x * 256 + threadIdx.x;
  int wid  = gid >> 6;
  int lane = threadIdx.x & 63;
  const float* src;
  float* dst;
  if (wid < NROWS) { src = z + (size_t)wid * DDIM;   dst = arow + wid; }
  else             { int r = wid - NROWS;
                     src = emb + (size_t)r * DDIM;   dst = cemb + r; }
  float4 v = *reinterpret_cast<const float4*>(src + lane * 4);
  float s = v.x * v.x + v.y * v.y;
  s += v.z * v.z;
  s += v.w * v.w;
  #pragma unroll
  for (int off = 1; off < 64; off <<= 1) s += __shfl_xor(s, off, 64);
  if (lane == 0) *dst = s;
}

// -------- emb f32 -> bf16, FRAGMENT-MAJOR (R13..R18-verified) -----------
// 16B-chunk o: g16 = o>>9 (16-cand group), s = (o>>6)&7 (k-tile),
// lane l = o&63 (lg=l>>4, l15=l&15). Chunk holds cand (g16*16+l15),
// k-range [(s*4+lg)*8, +8). Fragment (g16,s) = 1KB contiguous.
// Cand-chunk ch (32 cands) = g16 in {2ch, 2ch+1} = 16KB contiguous.
__global__ __launch_bounds__(256)
void vq_cvt(const float* __restrict__ emb, u16* __restrict__ e16) {
  int o   = blockIdx.x * 256 + threadIdx.x;   // 0 .. NE*32-1
  int g16 = o >> 9;
  int r   = o & 511;
  int s   = r >> 6;
  int l   = r & 63;
  int lg  = l >> 4, l15 = l & 15;
  int c   = g16 * 16 + l15;
  int kc  = s * 4 + lg;
  const float* src = emb + (size_t)c * DDIM + kc * 8;
  float4 v0 = *reinterpret_cast<const float4*>(src);
  float4 v1 = *reinterpret_cast<const float4*>(src + 4);
  u16 ov[8] = {f2bf(v0.x), f2bf(v0.y), f2bf(v0.z), f2bf(v0.w),
               f2bf(v1.x), f2bf(v1.y), f2bf(v1.z), f2bf(v1.w)};
  *reinterpret_cast<bf16x8*>(e16 + (size_t)o * 8) =
      *reinterpret_cast<bf16x8*>(ov);
}

// ---------------- MFMA approx pass + shortlist (counted vmcnt) ----------
// 8 waves: wm=wid>>1 (4 x 16-row group), wn=wid&1 (2 x 16-cand group).
// Per chunk per wave: 2 DMA loads, 8 b128 fragment reads, 8 MFMAs.
__global__ __launch_bounds__(512, 4)
void vq_mfma(const float* __restrict__ z, const u16* __restrict__ e16,
             const float* __restrict__ arow, const float* __restrict__ cemb,
             unsigned* __restrict__ cnt, int* __restrict__ list) {
  __shared__ char Bs[3][16384];   // 3 x 16 KB, fragment-major

  const int t    = threadIdx.x;
  const int R0   = blockIdx.x * BM;
  const int lane = t & 63;
  const int wid  = t >> 6;          // 0..7
  const int wm   = wid >> 1;        // 0..3 : 16-row group
  const int wn   = wid & 1;         // 0..1 : 16-cand group
  const int l15  = lane & 15;
  const int lg   = lane >> 4;       // 0..3

  // ---- A fragments: straight from global z, f32 -> bf16, in registers ----
  bf16x8 af[8];
  const int row = R0 + wm * 16 + l15;
  {
    const float* zr = z + (size_t)row * DDIM;
    #pragma unroll
    for (int s = 0; s < 8; ++s) {
      const float* src = zr + (s * 4 + lg) * 8;
      float4 v0 = *reinterpret_cast<const float4*>(src);
      float4 v1 = *reinterpret_cast<const float4*>(src + 4);
      u16 o[8] = {f2bf(v0.x), f2bf(v0.y), f2bf(v0.z), f2bf(v0.w),
                  f2bf(v1.x), f2bf(v1.y), f2bf(v1.z), f2bf(v1.w)};
      af[s] = *reinterpret_cast<bf16x8*>(o);
    }
  }
  const float a_r = arow[row];
  float runmin = 3.4e38f;

  // ---- prologue: issue DMA for chunks 0 and 1 (2 loads each/wave) ----
  {
    const char* src = (const char*)e16;
    #pragma unroll
    for (int i = 0; i < 2; ++i) {
      int f = wid * 2 + i;
      gload_lds16(src + f * 1024 + lane * 16, &Bs[0][0] + f * 1024);
    }
    #pragma unroll
    for (int i = 0; i < 2; ++i) {
      int f = wid * 2 + i;
      gload_lds16(src + 16384 + f * 1024 + lane * 16, &Bs[1][0] + f * 1024);
    }
  }

  for (int ch = 0; ch < NCH; ++ch) {
    // ---- counted wait: own chunk-ch loads landed (ch+1's stay in
    //      flight across the barrier -- never drain to 0 mid-loop) ----
    if (ch == NCH - 1) {
      asm volatile("s_waitcnt vmcnt(0)" ::: "memory");
    } else {
      asm volatile("s_waitcnt vmcnt(2)" ::: "memory");
    }
    __builtin_amdgcn_s_barrier();
    asm volatile("" ::: "memory");   // fence: no LDS reads hoist above

    // all waves passed vmcnt for ch => buf[ch%3] complete; all waves
    // finished reading buf[(ch+2)%3] (their iter ch-1) => safe to fill
    if (ch + 2 < NCH) {
      const char* src = (const char*)e16 + (size_t)(ch + 2) * 16384;
      char* dst = &Bs[(ch + 2) % 3][0];
      #pragma unroll
      for (int i = 0; i < 2; ++i) {
        int f = wid * 2 + i;
        gload_lds16(src + f * 1024 + lane * 16, dst + f * 1024);
      }
    }

    const int C0 = ch * 32;
    const float4 cvv = *reinterpret_cast<const float4*>(
        &cemb[C0 + wn * 16 + lg * 4]);

    // ---- compute: contiguous 1KB fragment reads, 8 MFMAs ----
    f32x4 acc = (f32x4){0.f, 0.f, 0.f, 0.f};
    const char* Bp = &Bs[ch % 3][0];
    #pragma unroll
    for (int s = 0; s < 8; ++s) {
      const bf16x8 bfr = *reinterpret_cast<const bf16x8*>(
          Bp + (wn * 8 + s) * 1024 + lane * 16);
      acc = __builtin_amdgcn_mfma_f32_16x16x32_bf16(bfr, af[s], acc, 0, 0, 0);
    }

    // ---- epilogue (regs + global only): row min, 2 shuffles, appends ----
    // lane's z-row = row; lane's cand (r) = C0 + wn*16 + lg*4 + r
    float lm = 3.4e38f;
    #pragma unroll
    for (int r = 0; r < 4; ++r) {
      float dd = fmaf(-2.0f, acc[r], a_r) + cvv[r];
      lm = fminf(lm, dd);
    }
    float gm = fminf(lm, __shfl_xor(lm, 16, 64));
    gm = fminf(gm, __shfl_xor(gm, 32, 64));
    runmin = fminf(runmin, gm);
    float thr = runmin + MARGIN;
    if (lm <= thr) {
      // u-form test (R5-verified): d<=thr <=> u >= 0.5*(a+c-thr)
      const float h = 0.5f * (a_r - thr);
      #pragma unroll
      for (int r = 0; r < 4; ++r)
        if (acc[r] >= fmaf(0.5f, cvv[r], h)) {
          int k = C0 + wn * 16 + lg * 4 + r;
          unsigned p = atomicAdd(&cnt[row], 1u);
          if (p < CAP) list[(size_t)row * CAP + p] = k;
        }
    }
  }
}

// ---------------- exact f32 rescore of shortlists (R15-verified) --------
__global__ __launch_bounds__(256)
void vq_rescore(const float* __restrict__ z, const float* __restrict__ emb,
                const float* __restrict__ arow, const float* __restrict__ cemb,
                const unsigned* __restrict__ cnt, const int* __restrict__ list,
                int* __restrict__ ws_idx) {
  const int row  = blockIdx.x * 4 + (threadIdx.x >> 6);
  const int lane = threadIdx.x & 63;
  const float a  = arow[row];
  const float4 zv = *reinterpret_cast<const float4*>(
      z + (size_t)row * DDIM + lane * 4);
  unsigned n = cnt[row];
  float bd = 3.4e38f;
  int   bk = 0;

  const bool fullscan = (n == 0 || n > CAP);
  const int  m = fullscan ? NE : (int)n;
  for (int i = 0; i < m; ++i) {
    int k = fullscan ? i : list[(size_t)row * CAP + i];
    const float4 ev = *reinterpret_cast<const float4*>(
        emb + (size_t)k * DDIM + lane * 4);
    float p = zv.x * ev.x;
    p = fmaf(zv.y, ev.y, p);
    p = fmaf(zv.z, ev.z, p);
    p = fmaf(zv.w, ev.w, p);
    #pragma unroll
    for (int off = 1; off < 64; off <<= 1) p += __shfl_xor(p, off, 64);
    float d = fmaf(-2.0f, p, a) + cemb[k];   // exact ref chain
    if (d < bd || (d == bd && k < bk)) { bd = d; bk = k; }
  }
  if (lane == 0) ws_idx[row] = bk;
}

// -------- gather + STE + losses (float4-vectorized, 1 wave/row) ---------
__global__ __launch_bounds__(256)
void vq_gather(const float* __restrict__ z, const float* __restrict__ emb,
               const int* __restrict__ ws_idx,
               float* __restrict__ out_zq, float* __restrict__ out_idx,
               double* __restrict__ loss_accum) {
  __shared__ float part[4];
  const int t    = threadIdx.x;
  const int wid  = t >> 6;
  const int lane = t & 63;
  const int R0   = blockIdx.x * 64;
  float lsum = 0.0f;
  for (int rr = 0; rr < 16; ++rr) {
    const int row = R0 + rr * 4 + wid;
    const int kb  = ws_idx[row];
    const float4 zv = *reinterpret_cast<const float4*>(
        z + (size_t)row * DDIM + lane * 4);
    const float4 ev = *reinterpret_cast<const float4*>(
        emb + (size_t)kb * DDIM + lane * 4);
    float dx = ev.x - zv.x;                // z_q - z (exact ref chain)
    float dy = ev.y - zv.y;
    float dz = ev.z - zv.z;
    float dw = ev.w - zv.w;
    float4 o = {zv.x + dx, zv.y + dy, zv.z + dz, zv.w + dw};
    *reinterpret_cast<float4*>(out_zq + (size_t)row * DDIM + lane * 4) = o;
    lsum = fmaf(dx, dx, lsum);
    lsum = fmaf(dy, dy, lsum);
    lsum = fmaf(dz, dz, lsum);
    lsum = fmaf(dw, dw, lsum);
  }
  #pragma unroll
  for (int off = 1; off < 64; off <<= 1) lsum += __shfl_xor(lsum, off, 64);
  if (lane == 0) part[wid] = lsum;
  __syncthreads();
  if (t == 0) {
    float tot = (part[0] + part[1]) + (part[2] + part[3]);
    atomicAdd(loss_accum, (double)tot);
  }
  if (t < 64) out_idx[R0 + t] = (float)ws_idx[R0 + t];
}

// ---------------- scalar losses -----------------------------------------
__global__ void vq_finalize(const double* __restrict__ loss_accum,
                            float* __restrict__ out_losses) {
  double m = *loss_accum / (double)((size_t)NROWS * DDIM);
  out_losses[0] = (float)(0.25 * m);   // loss_commit = BETA * mse
  out_losses[1] = (float)m;            // loss_codebook
}

extern "C" void kernel_launch(void* const* d_in, const int* in_sizes, int n_in,
                              void* d_out, int out_size, void* d_ws, size_t ws_size,
                              hipStream_t stream) {
  const float* z   = (const float*)d_in[0];
  const float* emb = (const float*)d_in[1];
  float* out        = (float*)d_out;
  float* out_zq     = out;                            // [8388608]
  float* out_losses = out + (size_t)NROWS * DDIM;     // [2]
  float* out_idx    = out + (size_t)NROWS * DDIM + 2; // [32768] as f32

  // persistent ws scratch (small)
  double* loss_accum = (double*)d_ws;
  float*  arow   = (float*)((char*)d_ws + 256);
  float*  cemb   = arow + NROWS;
  int*    ws_idx = (int*)(cemb + NE);

  // large scratch carved from d_out's z_q region (fully rewritten each call;
  // vq_gather overwrites only after rescore consumed list/cnt => safe)
  u16*      e16  = (u16*)d_out;                              // [0, 4MB)
  int*      list = (int*)((char*)d_out + (4 << 20));         // [4MB, 12MB) CAP=64
  unsigned* cnt  = (unsigned*)((char*)d_out + (12 << 20));   // [12MB, +128KB)

  hipMemsetAsync(d_ws, 0, 8, stream);
  hipMemsetAsync(cnt, 0, NROWS * sizeof(unsigned), stream);
  vq_norms<<<(NROWS + NE) / 4, 256, 0, stream>>>(z, emb, arow, cemb);
  vq_cvt<<<NE * 32 / 256, 256, 0, stream>>>(emb, e16);
  vq_mfma<<<NROWS / BM, 512, 0, stream>>>(z, e16, arow, cemb, cnt, list);
  vq_rescore<<<NROWS / 4, 256, 0, stream>>>(z, emb, arow, cemb, cnt, list, ws_idx);
  vq_gather<<<NROWS / 64, 256, 0, stream>>>(z, emb, ws_idx,
                                            out_zq, out_idx, loss_accum);
  vq_finalize<<<1, 1, 0, stream>>>(loss_accum, out_losses);
}

// Round 22
// 308.354 us; speedup vs baseline: 1.5612x; 1.2213x over previous
//
#include <hip/hip_runtime.h>

// VectorQuantizer: bf16-MFMA approximate distance pass + margin shortlist +
// exact f32 rescore (+fused gather when scratch permits) + losses.
// N=32768, D=256, K=8192.
//
// R22 = R18 (321us proven) + SAFE rescore/gather fusion:
// R17's fusion crashed only because list/cnt were carved under out_zq
// (fused kernel wrote z_q while other blocks still read list). Fix: if
// ws_size >= 14MB, put ALL scratch (e16 4MB, list 8MB, cnt, arow, cemb,
// loss parts) in d_ws -- d_out never aliased -> fusion is hazard-free
// (saves gather's 33MB z re-read + a launch). Else: R18's separate-kernel
// path verbatim (R21's neutral float4 gather). Branch on ws_size is
// per-process constant => deterministic & graph-safe.
// vq_norms / vq_cvt / vq_mfma identical to R18 in both paths.
// R21 lesson: counted-vmcnt NULL here (DMA 4KB/wave lands well within the
// 2500cyc compute window from hot L2; halving chunks doubled overhead).

#define NROWS 32768
#define NE    8192
#define DDIM  256
#define BM    64
#define CAP   64
#define MARGIN 1e-4f
#define NCH   (NE / 64)    // 128 chunks of 64 candidates

typedef __attribute__((ext_vector_type(8))) short bf16x8;
typedef __attribute__((ext_vector_type(4))) float f32x4;
typedef unsigned short u16;

__device__ __forceinline__ u16 f2bf(float f) {
  unsigned x = __float_as_uint(f);
  return (u16)((x + 0x7fffu + ((x >> 16) & 1u)) >> 16);   // RNE
}

__device__ __forceinline__ void gload_lds16(const void* g, void* l) {
  __builtin_amdgcn_global_load_lds(
      (const __attribute__((address_space(1))) void*)g,
      (__attribute__((address_space(3))) void*)l, 16, 0, 0);
}

// ---------------- row norms: a[n] = sum z^2, c[k] = sum e^2 -------------
__global__ __launch_bounds__(256)
void vq_norms(const float* __restrict__ z, const float* __restrict__ emb,
              float* __restrict__ arow, float* __restrict__ cemb) {
  int gid  = blockIdx.x * 256 + threadIdx.x;
  int wid  = gid >> 6;
  int lane = threadIdx.x & 63;
  const float* src;
  float* dst;
  if (wid < NROWS) { src = z + (size_t)wid * DDIM;   dst = arow + wid; }
  else             { int r = wid - NROWS;
                     src = emb + (size_t)r * DDIM;   dst = cemb + r; }
  float4 v = *reinterpret_cast<const float4*>(src + lane * 4);
  float s = v.x * v.x + v.y * v.y;
  s += v.z * v.z;
  s += v.w * v.w;
  #pragma unroll
  for (int off = 1; off < 64; off <<= 1) s += __shfl_xor(s, off, 64);
  if (lane == 0) *dst = s;
}

// -------- emb f32 -> bf16, FRAGMENT-MAJOR (R13..R18-verified) -----------
__global__ __launch_bounds__(256)
void vq_cvt(const float* __restrict__ emb, u16* __restrict__ e16) {
  int o   = blockIdx.x * 256 + threadIdx.x;   // 0 .. NE*32-1
  int g16 = o >> 9;
  int r   = o & 511;
  int s   = r >> 6;
  int l   = r & 63;
  int lg  = l >> 4, l15 = l & 15;
  int c   = g16 * 16 + l15;
  int kc  = s * 4 + lg;
  const float* src = emb + (size_t)c * DDIM + kc * 8;
  float4 v0 = *reinterpret_cast<const float4*>(src);
  float4 v1 = *reinterpret_cast<const float4*>(src + 4);
  u16 ov[8] = {f2bf(v0.x), f2bf(v0.y), f2bf(v0.z), f2bf(v0.w),
               f2bf(v1.x), f2bf(v1.y), f2bf(v1.z), f2bf(v1.w)};
  *reinterpret_cast<bf16x8*>(e16 + (size_t)o * 8) =
      *reinterpret_cast<bf16x8*>(ov);
}

// ---------------- MFMA approx pass + shortlist (R18 verbatim) -----------
__global__ __launch_bounds__(512, 4)
void vq_mfma(const float* __restrict__ z, const u16* __restrict__ e16,
             const float* __restrict__ arow, const float* __restrict__ cemb,
             unsigned* __restrict__ cnt, int* __restrict__ list) {
  __shared__ u16 Bs[2][64 * DDIM];   // 2 x 32 KB, fragment-major

  const int t    = threadIdx.x;
  const int R0   = blockIdx.x * BM;
  const int lane = t & 63;
  const int wid  = t >> 6;          // 0..7
  const int wm   = wid >> 1;        // 0..3 : 16-row group
  const int wn   = wid & 1;         // 0..1 : 32-cand half
  const int l15  = lane & 15;
  const int lg   = lane >> 4;       // 0..3

  bf16x8 af[8];
  const int row = R0 + wm * 16 + l15;
  {
    const float* zr = z + (size_t)row * DDIM;
    #pragma unroll
    for (int s = 0; s < 8; ++s) {
      const float* src = zr + (s * 4 + lg) * 8;
      float4 v0 = *reinterpret_cast<const float4*>(src);
      float4 v1 = *reinterpret_cast<const float4*>(src + 4);
      u16 o[8] = {f2bf(v0.x), f2bf(v0.y), f2bf(v0.z), f2bf(v0.w),
                  f2bf(v1.x), f2bf(v1.y), f2bf(v1.z), f2bf(v1.w)};
      af[s] = *reinterpret_cast<bf16x8*>(o);
    }
  }
  const float a_r = arow[row];
  float runmin = 3.4e38f;

  {
    const char* src = (const char*)e16;
    #pragma unroll
    for (int i = 0; i < 4; ++i) {
      int f = wid * 4 + i;
      gload_lds16(src + f * 1024 + lane * 16, (char*)&Bs[0][0] + f * 1024);
    }
  }
  __syncthreads();   // drains prologue DMA

  for (int ch = 0; ch < NCH; ++ch) {
    const int buf = ch & 1;
    const int C0  = ch * 64;

    if (ch + 1 < NCH) {
      const char* src = (const char*)e16 + (size_t)(ch + 1) * 32768;
      char* dst = (char*)&Bs[buf ^ 1][0];
      #pragma unroll
      for (int i = 0; i < 4; ++i) {
        int f = wid * 4 + i;
        gload_lds16(src + f * 1024 + lane * 16, dst + f * 1024);
      }
    }

    float4 cvv[2];
    #pragma unroll
    for (int ci = 0; ci < 2; ++ci)
      cvv[ci] = *reinterpret_cast<const float4*>(
          &cemb[C0 + wn * 32 + ci * 16 + lg * 4]);

    f32x4 acc[2];
    acc[0] = (f32x4){0.f, 0.f, 0.f, 0.f};
    acc[1] = (f32x4){0.f, 0.f, 0.f, 0.f};

    const u16* Bp = &Bs[buf][0];
    #pragma unroll
    for (int s = 0; s < 8; ++s) {
      bf16x8 bfr[2];
      #pragma unroll
      for (int ci = 0; ci < 2; ++ci)
        bfr[ci] = *reinterpret_cast<const bf16x8*>(
            &Bp[((wn * 2 + ci) * 8 + s) * 512 + lane * 8]);
      #pragma unroll
      for (int ci = 0; ci < 2; ++ci)
        acc[ci] = __builtin_amdgcn_mfma_f32_16x16x32_bf16(
            bfr[ci], af[s], acc[ci], 0, 0, 0);
    }

    __syncthreads();   // compute(buf) done by ALL waves; next DMA drained

    // ---- POST-BARRIER epilogue (regs + global only, no LDS) ----
    float lm = 3.4e38f;
    #pragma unroll
    for (int ci = 0; ci < 2; ++ci)
      #pragma unroll
      for (int r = 0; r < 4; ++r) {
        float dd = fmaf(-2.0f, acc[ci][r], a_r) + cvv[ci][r];
        lm = fminf(lm, dd);
      }
    float gm = fminf(lm, __shfl_xor(lm, 16, 64));
    gm = fminf(gm, __shfl_xor(gm, 32, 64));
    runmin = fminf(runmin, gm);
    float thr = runmin + MARGIN;
    if (lm <= thr) {
      // u-form test (R5-verified): d<=thr <=> u >= 0.5*(a+c-thr)
      const float h = 0.5f * (a_r - thr);
      #pragma unroll
      for (int ci = 0; ci < 2; ++ci)
        #pragma unroll
        for (int r = 0; r < 4; ++r)
          if (acc[ci][r] >= fmaf(0.5f, cvv[ci][r], h)) {
            int k = C0 + wn * 32 + ci * 16 + lg * 4 + r;
            unsigned p = atomicAdd(&cnt[row], 1u);
            if (p < CAP) list[(size_t)row * CAP + p] = k;
          }
    }
  }
}

// -------- FUSED exact rescore + gather + STE + loss (big-ws path) -------
// Scratch entirely in d_ws => out_zq never aliases list/cnt => safe.
__global__ __launch_bounds__(256)
void vq_rescore_fused(const float* __restrict__ z, const float* __restrict__ emb,
                      const float* __restrict__ arow, const float* __restrict__ cemb,
                      const unsigned* __restrict__ cnt, const int* __restrict__ list,
                      float* __restrict__ out_zq, float* __restrict__ out_idx,
                      double* __restrict__ part) {
  __shared__ float part4[4];
  const int wid  = threadIdx.x >> 6;
  const int row  = blockIdx.x * 4 + wid;
  const int lane = threadIdx.x & 63;
  const float a  = arow[row];
  const float4 zv = *reinterpret_cast<const float4*>(
      z + (size_t)row * DDIM + lane * 4);
  unsigned n = cnt[row];
  float bd = 3.4e38f;
  int   bk = 0;

  if (n != 0 && n <= CAP) {
    // common path: serial scan, BIT-IDENTICAL chain to R5..R18 (verified)
    for (int i = 0; i < (int)n; ++i) {
      int k = list[(size_t)row * CAP + i];
      const float4 ev = *reinterpret_cast<const float4*>(
          emb + (size_t)k * DDIM + lane * 4);
      float p = zv.x * ev.x;
      p = fmaf(zv.y, ev.y, p);
      p = fmaf(zv.z, ev.z, p);
      p = fmaf(zv.w, ev.w, p);
      #pragma unroll
      for (int off = 1; off < 64; off <<= 1) p += __shfl_xor(p, off, 64);
      float d = fmaf(-2.0f, p, a) + cemb[k];
      if (d < bd || (d == bd && k < bk)) { bd = d; bk = k; }
    }
  } else {
    // overflow fallback (statistically never): full scan, same chain
    for (int i = 0; i < NE; ++i) {
      const float4 ev = *reinterpret_cast<const float4*>(
          emb + (size_t)i * DDIM + lane * 4);
      float p = zv.x * ev.x;
      p = fmaf(zv.y, ev.y, p);
      p = fmaf(zv.z, ev.z, p);
      p = fmaf(zv.w, ev.w, p);
      #pragma unroll
      for (int off = 1; off < 64; off <<= 1) p += __shfl_xor(p, off, 64);
      float d = fmaf(-2.0f, p, a) + cemb[i];
      if (d < bd) { bd = d; bk = i; }   // ascending i: strict < keeps first
    }
  }

  // ---- fused gather + STE + loss (winner row L2-hot; zv already held) ----
  const float4 ev = *reinterpret_cast<const float4*>(
      emb + (size_t)bk * DDIM + lane * 4);
  float dx = ev.x - zv.x;                 // z_q - z (exact ref chain)
  float dy = ev.y - zv.y;
  float dz = ev.z - zv.z;
  float dw = ev.w - zv.w;
  float4 o = {zv.x + dx, zv.y + dy, zv.z + dz, zv.w + dw};  // z + (z_q - z)
  *reinterpret_cast<float4*>(out_zq + (size_t)row * DDIM + lane * 4) = o;
  float lsum = dx * dx;
  lsum = fmaf(dy, dy, lsum);
  lsum = fmaf(dz, dz, lsum);
  lsum = fmaf(dw, dw, lsum);
  #pragma unroll
  for (int off = 1; off < 64; off <<= 1) lsum += __shfl_xor(lsum, off, 64);
  if (lane == 0) {
    part4[wid] = lsum;
    out_idx[row] = (float)bk;
  }
  __syncthreads();
  if (threadIdx.x == 0) {
    float tot = (part4[0] + part4[1]) + (part4[2] + part4[3]);
    atomicAdd(&part[blockIdx.x & 255], (double)tot);
  }
}

__global__ void vq_finalize_fused(const double* __restrict__ part,
                                  float* __restrict__ out_losses) {
  int lane = threadIdx.x & 63;
  double s = part[lane] + part[lane + 64] + part[lane + 128] + part[lane + 192];
  #pragma unroll
  for (int off = 1; off < 64; off <<= 1) s += __shfl_xor(s, off, 64);
  if (lane == 0) {
    double m = s / (double)((size_t)NROWS * DDIM);
    out_losses[0] = (float)(0.25 * m);   // loss_commit = BETA * mse
    out_losses[1] = (float)m;            // loss_codebook
  }
}

// ---------------- R18 fallback path (small ws): separate kernels --------
__global__ __launch_bounds__(256)
void vq_rescore(const float* __restrict__ z, const float* __restrict__ emb,
                const float* __restrict__ arow, const float* __restrict__ cemb,
                const unsigned* __restrict__ cnt, const int* __restrict__ list,
                int* __restrict__ ws_idx) {
  const int row  = blockIdx.x * 4 + (threadIdx.x >> 6);
  const int lane = threadIdx.x & 63;
  const float a  = arow[row];
  const float4 zv = *reinterpret_cast<const float4*>(
      z + (size_t)row * DDIM + lane * 4);
  unsigned n = cnt[row];
  float bd = 3.4e38f;
  int   bk = 0;
  const bool fullscan = (n == 0 || n > CAP);
  const int  m = fullscan ? NE : (int)n;
  for (int i = 0; i < m; ++i) {
    int k = fullscan ? i : list[(size_t)row * CAP + i];
    const float4 ev = *reinterpret_cast<const float4*>(
        emb + (size_t)k * DDIM + lane * 4);
    float p = zv.x * ev.x;
    p = fmaf(zv.y, ev.y, p);
    p = fmaf(zv.z, ev.z, p);
    p = fmaf(zv.w, ev.w, p);
    #pragma unroll
    for (int off = 1; off < 64; off <<= 1) p += __shfl_xor(p, off, 64);
    float d = fmaf(-2.0f, p, a) + cemb[k];
    if (d < bd || (d == bd && k < bk)) { bd = d; bk = k; }
  }
  if (lane == 0) ws_idx[row] = bk;
}

__global__ __launch_bounds__(256)
void vq_gather(const float* __restrict__ z, const float* __restrict__ emb,
               const int* __restrict__ ws_idx,
               float* __restrict__ out_zq, float* __restrict__ out_idx,
               double* __restrict__ loss_accum) {
  __shared__ float part[4];
  const int t    = threadIdx.x;
  const int wid  = t >> 6;
  const int lane = t & 63;
  const int R0   = blockIdx.x * 64;
  float lsum = 0.0f;
  for (int rr = 0; rr < 16; ++rr) {
    const int row = R0 + rr * 4 + wid;
    const int kb  = ws_idx[row];
    const float4 zv = *reinterpret_cast<const float4*>(
        z + (size_t)row * DDIM + lane * 4);
    const float4 ev = *reinterpret_cast<const float4*>(
        emb + (size_t)kb * DDIM + lane * 4);
    float dx = ev.x - zv.x;
    float dy = ev.y - zv.y;
    float dz = ev.z - zv.z;
    float dw = ev.w - zv.w;
    float4 o = {zv.x + dx, zv.y + dy, zv.z + dz, zv.w + dw};
    *reinterpret_cast<float4*>(out_zq + (size_t)row * DDIM + lane * 4) = o;
    lsum = fmaf(dx, dx, lsum);
    lsum = fmaf(dy, dy, lsum);
    lsum = fmaf(dz, dz, lsum);
    lsum = fmaf(dw, dw, lsum);
  }
  #pragma unroll
  for (int off = 1; off < 64; off <<= 1) lsum += __shfl_xor(lsum, off, 64);
  if (lane == 0) part[wid] = lsum;
  __syncthreads();
  if (t == 0) {
    float tot = (part[0] + part[1]) + (part[2] + part[3]);
    atomicAdd(loss_accum, (double)tot);
  }
  if (t < 64) out_idx[R0 + t] = (float)ws_idx[R0 + t];
}

__global__ void vq_finalize(const double* __restrict__ loss_accum,
                            float* __restrict__ out_losses) {
  double m = *loss_accum / (double)((size_t)NROWS * DDIM);
  out_losses[0] = (float)(0.25 * m);
  out_losses[1] = (float)m;
}

extern "C" void kernel_launch(void* const* d_in, const int* in_sizes, int n_in,
                              void* d_out, int out_size, void* d_ws, size_t ws_size,
                              hipStream_t stream) {
  const float* z   = (const float*)d_in[0];
  const float* emb = (const float*)d_in[1];
  float* out        = (float*)d_out;
  float* out_zq     = out;                            // [8388608]
  float* out_losses = out + (size_t)NROWS * DDIM;     // [2]
  float* out_idx    = out + (size_t)NROWS * DDIM + 2; // [32768] as f32

  const bool big_ws = ws_size >= (size_t)(14u << 20);

  if (big_ws) {
    // ---- all scratch in d_ws; d_out never aliased => fused tail ----
    char* w = (char*)d_ws;
    double*   part = (double*)w;                      // [256] @ 0 (2KB)
    float*    arow = (float*)(w + 4096);              // 128KB
    float*    cemb = (float*)(w + 4096 + 131072);     // 32KB
    unsigned* cnt  = (unsigned*)(w + 4096 + 131072 + 32768);  // 128KB
    u16*      e16  = (u16*)(w + (1u << 20));          // 4MB @ 1MB
    int*      list = (int*)(w + (5u << 20));          // 8MB @ 5MB

    hipMemsetAsync(part, 0, 2048, stream);
    hipMemsetAsync(cnt, 0, NROWS * sizeof(unsigned), stream);
    vq_norms<<<(NROWS + NE) / 4, 256, 0, stream>>>(z, emb, arow, cemb);
    vq_cvt<<<NE * 32 / 256, 256, 0, stream>>>(emb, e16);
    vq_mfma<<<NROWS / BM, 512, 0, stream>>>(z, e16, arow, cemb, cnt, list);
    vq_rescore_fused<<<NROWS / 4, 256, 0, stream>>>(z, emb, arow, cemb,
                                                    cnt, list,
                                                    out_zq, out_idx, part);
    vq_finalize_fused<<<1, 64, 0, stream>>>(part, out_losses);
  } else {
    // ---- R18 fallback: scratch carved from d_out, separate kernels ----
    double* loss_accum = (double*)d_ws;
    float*  arow   = (float*)((char*)d_ws + 256);
    float*  cemb   = arow + NROWS;
    int*    ws_idx = (int*)(cemb + NE);

    u16*      e16  = (u16*)d_out;                            // [0, 4MB)
    int*      list = (int*)((char*)d_out + (4 << 20));       // [4MB, 12MB)
    unsigned* cnt  = (unsigned*)((char*)d_out + (12 << 20)); // [12MB, +128KB)

    hipMemsetAsync(d_ws, 0, 8, stream);
    hipMemsetAsync(cnt, 0, NROWS * sizeof(unsigned), stream);
    vq_norms<<<(NROWS + NE) / 4, 256, 0, stream>>>(z, emb, arow, cemb);
    vq_cvt<<<NE * 32 / 256, 256, 0, stream>>>(emb, e16);
    vq_mfma<<<NROWS / BM, 512, 0, stream>>>(z, e16, arow, cemb, cnt, list);
    vq_rescore<<<NROWS / 4, 256, 0, stream>>>(z, emb, arow, cemb, cnt, list,
                                              ws_idx);
    vq_gather<<<NROWS / 64, 256, 0, stream>>>(z, emb, ws_idx,
                                              out_zq, out_idx, loss_accum);
    vq_finalize<<<1, 1, 0, stream>>>(loss_accum, out_losses);
  }
}

// Round 23
// 295.924 us; speedup vs baseline: 1.6267x; 1.0420x over previous
//
#include <hip/hip_runtime.h>

// VectorQuantizer: bf16-MFMA approximate distance pass + margin shortlist +
// exact f32 rescore (+fused gather when scratch permits) + losses.
// N=32768, D=256, K=8192.
//
// R23 = R22 (308us best) + ONE change: T5 s_setprio(1) around vq_mfma's
// MFMA cluster. Rationale: 2 blocks/CU run naturally desynchronized
// (R8-proven mechanism); T5 pays exactly when co-resident waves are at
// DIFFERENT phases (guide m191: +4-7% attn). A wave entering its MFMA
// burst gets issue priority over the other block's DMA/epilogue waves.
// Zero correctness surface (scheduler hint only).
// Ceiling note: vq_mfma wall 244us vs LDS-BW floor 134us; all structural
// paths to close it (zi>=2, 32x32, fp8, counted-vmcnt) regressed under
// the toolchain's VGPR/occupancy envelope. T5 is the last catalog lever.

#define NROWS 32768
#define NE    8192
#define DDIM  256
#define BM    64
#define CAP   64
#define MARGIN 1e-4f
#define NCH   (NE / 64)    // 128 chunks of 64 candidates

typedef __attribute__((ext_vector_type(8))) short bf16x8;
typedef __attribute__((ext_vector_type(4))) float f32x4;
typedef unsigned short u16;

__device__ __forceinline__ u16 f2bf(float f) {
  unsigned x = __float_as_uint(f);
  return (u16)((x + 0x7fffu + ((x >> 16) & 1u)) >> 16);   // RNE
}

__device__ __forceinline__ void gload_lds16(const void* g, void* l) {
  __builtin_amdgcn_global_load_lds(
      (const __attribute__((address_space(1))) void*)g,
      (__attribute__((address_space(3))) void*)l, 16, 0, 0);
}

// ---------------- row norms: a[n] = sum z^2, c[k] = sum e^2 -------------
__global__ __launch_bounds__(256)
void vq_norms(const float* __restrict__ z, const float* __restrict__ emb,
              float* __restrict__ arow, float* __restrict__ cemb) {
  int gid  = blockIdx.x * 256 + threadIdx.x;
  int wid  = gid >> 6;
  int lane = threadIdx.x & 63;
  const float* src;
  float* dst;
  if (wid < NROWS) { src = z + (size_t)wid * DDIM;   dst = arow + wid; }
  else             { int r = wid - NROWS;
                     src = emb + (size_t)r * DDIM;   dst = cemb + r; }
  float4 v = *reinterpret_cast<const float4*>(src + lane * 4);
  float s = v.x * v.x + v.y * v.y;
  s += v.z * v.z;
  s += v.w * v.w;
  #pragma unroll
  for (int off = 1; off < 64; off <<= 1) s += __shfl_xor(s, off, 64);
  if (lane == 0) *dst = s;
}

// -------- emb f32 -> bf16, FRAGMENT-MAJOR (R13..R18-verified) -----------
__global__ __launch_bounds__(256)
void vq_cvt(const float* __restrict__ emb, u16* __restrict__ e16) {
  int o   = blockIdx.x * 256 + threadIdx.x;   // 0 .. NE*32-1
  int g16 = o >> 9;
  int r   = o & 511;
  int s   = r >> 6;
  int l   = r & 63;
  int lg  = l >> 4, l15 = l & 15;
  int c   = g16 * 16 + l15;
  int kc  = s * 4 + lg;
  const float* src = emb + (size_t)c * DDIM + kc * 8;
  float4 v0 = *reinterpret_cast<const float4*>(src);
  float4 v1 = *reinterpret_cast<const float4*>(src + 4);
  u16 ov[8] = {f2bf(v0.x), f2bf(v0.y), f2bf(v0.z), f2bf(v0.w),
               f2bf(v1.x), f2bf(v1.y), f2bf(v1.z), f2bf(v1.w)};
  *reinterpret_cast<bf16x8*>(e16 + (size_t)o * 8) =
      *reinterpret_cast<bf16x8*>(ov);
}

// ---------------- MFMA approx pass + shortlist (R18 + T5 setprio) -------
__global__ __launch_bounds__(512, 4)
void vq_mfma(const float* __restrict__ z, const u16* __restrict__ e16,
             const float* __restrict__ arow, const float* __restrict__ cemb,
             unsigned* __restrict__ cnt, int* __restrict__ list) {
  __shared__ u16 Bs[2][64 * DDIM];   // 2 x 32 KB, fragment-major

  const int t    = threadIdx.x;
  const int R0   = blockIdx.x * BM;
  const int lane = t & 63;
  const int wid  = t >> 6;          // 0..7
  const int wm   = wid >> 1;        // 0..3 : 16-row group
  const int wn   = wid & 1;         // 0..1 : 32-cand half
  const int l15  = lane & 15;
  const int lg   = lane >> 4;       // 0..3

  bf16x8 af[8];
  const int row = R0 + wm * 16 + l15;
  {
    const float* zr = z + (size_t)row * DDIM;
    #pragma unroll
    for (int s = 0; s < 8; ++s) {
      const float* src = zr + (s * 4 + lg) * 8;
      float4 v0 = *reinterpret_cast<const float4*>(src);
      float4 v1 = *reinterpret_cast<const float4*>(src + 4);
      u16 o[8] = {f2bf(v0.x), f2bf(v0.y), f2bf(v0.z), f2bf(v0.w),
                  f2bf(v1.x), f2bf(v1.y), f2bf(v1.z), f2bf(v1.w)};
      af[s] = *reinterpret_cast<bf16x8*>(o);
    }
  }
  const float a_r = arow[row];
  float runmin = 3.4e38f;

  {
    const char* src = (const char*)e16;
    #pragma unroll
    for (int i = 0; i < 4; ++i) {
      int f = wid * 4 + i;
      gload_lds16(src + f * 1024 + lane * 16, (char*)&Bs[0][0] + f * 1024);
    }
  }
  __syncthreads();   // drains prologue DMA

  for (int ch = 0; ch < NCH; ++ch) {
    const int buf = ch & 1;
    const int C0  = ch * 64;

    if (ch + 1 < NCH) {
      const char* src = (const char*)e16 + (size_t)(ch + 1) * 32768;
      char* dst = (char*)&Bs[buf ^ 1][0];
      #pragma unroll
      for (int i = 0; i < 4; ++i) {
        int f = wid * 4 + i;
        gload_lds16(src + f * 1024 + lane * 16, dst + f * 1024);
      }
    }

    float4 cvv[2];
    #pragma unroll
    for (int ci = 0; ci < 2; ++ci)
      cvv[ci] = *reinterpret_cast<const float4*>(
          &cemb[C0 + wn * 32 + ci * 16 + lg * 4]);

    f32x4 acc[2];
    acc[0] = (f32x4){0.f, 0.f, 0.f, 0.f};
    acc[1] = (f32x4){0.f, 0.f, 0.f, 0.f};

    // ---- T5: priority-boost the MFMA cluster (2 blk/CU are desynced) ----
    __builtin_amdgcn_s_setprio(1);
    const u16* Bp = &Bs[buf][0];
    #pragma unroll
    for (int s = 0; s < 8; ++s) {
      bf16x8 bfr[2];
      #pragma unroll
      for (int ci = 0; ci < 2; ++ci)
        bfr[ci] = *reinterpret_cast<const bf16x8*>(
            &Bp[((wn * 2 + ci) * 8 + s) * 512 + lane * 8]);
      #pragma unroll
      for (int ci = 0; ci < 2; ++ci)
        acc[ci] = __builtin_amdgcn_mfma_f32_16x16x32_bf16(
            bfr[ci], af[s], acc[ci], 0, 0, 0);
    }
    __builtin_amdgcn_s_setprio(0);

    __syncthreads();   // compute(buf) done by ALL waves; next DMA drained

    // ---- POST-BARRIER epilogue (regs + global only, no LDS) ----
    float lm = 3.4e38f;
    #pragma unroll
    for (int ci = 0; ci < 2; ++ci)
      #pragma unroll
      for (int r = 0; r < 4; ++r) {
        float dd = fmaf(-2.0f, acc[ci][r], a_r) + cvv[ci][r];
        lm = fminf(lm, dd);
      }
    float gm = fminf(lm, __shfl_xor(lm, 16, 64));
    gm = fminf(gm, __shfl_xor(gm, 32, 64));
    runmin = fminf(runmin, gm);
    float thr = runmin + MARGIN;
    if (lm <= thr) {
      // u-form test (R5-verified): d<=thr <=> u >= 0.5*(a+c-thr)
      const float h = 0.5f * (a_r - thr);
      #pragma unroll
      for (int ci = 0; ci < 2; ++ci)
        #pragma unroll
        for (int r = 0; r < 4; ++r)
          if (acc[ci][r] >= fmaf(0.5f, cvv[ci][r], h)) {
            int k = C0 + wn * 32 + ci * 16 + lg * 4 + r;
            unsigned p = atomicAdd(&cnt[row], 1u);
            if (p < CAP) list[(size_t)row * CAP + p] = k;
          }
    }
  }
}

// -------- FUSED exact rescore + gather + STE + loss (big-ws path) -------
__global__ __launch_bounds__(256)
void vq_rescore_fused(const float* __restrict__ z, const float* __restrict__ emb,
                      const float* __restrict__ arow, const float* __restrict__ cemb,
                      const unsigned* __restrict__ cnt, const int* __restrict__ list,
                      float* __restrict__ out_zq, float* __restrict__ out_idx,
                      double* __restrict__ part) {
  __shared__ float part4[4];
  const int wid  = threadIdx.x >> 6;
  const int row  = blockIdx.x * 4 + wid;
  const int lane = threadIdx.x & 63;
  const float a  = arow[row];
  const float4 zv = *reinterpret_cast<const float4*>(
      z + (size_t)row * DDIM + lane * 4);
  unsigned n = cnt[row];
  float bd = 3.4e38f;
  int   bk = 0;

  if (n != 0 && n <= CAP) {
    // common path: serial scan, BIT-IDENTICAL chain to R5..R22 (verified)
    for (int i = 0; i < (int)n; ++i) {
      int k = list[(size_t)row * CAP + i];
      const float4 ev = *reinterpret_cast<const float4*>(
          emb + (size_t)k * DDIM + lane * 4);
      float p = zv.x * ev.x;
      p = fmaf(zv.y, ev.y, p);
      p = fmaf(zv.z, ev.z, p);
      p = fmaf(zv.w, ev.w, p);
      #pragma unroll
      for (int off = 1; off < 64; off <<= 1) p += __shfl_xor(p, off, 64);
      float d = fmaf(-2.0f, p, a) + cemb[k];
      if (d < bd || (d == bd && k < bk)) { bd = d; bk = k; }
    }
  } else {
    // overflow fallback (statistically never): full scan, same chain
    for (int i = 0; i < NE; ++i) {
      const float4 ev = *reinterpret_cast<const float4*>(
          emb + (size_t)i * DDIM + lane * 4);
      float p = zv.x * ev.x;
      p = fmaf(zv.y, ev.y, p);
      p = fmaf(zv.z, ev.z, p);
      p = fmaf(zv.w, ev.w, p);
      #pragma unroll
      for (int off = 1; off < 64; off <<= 1) p += __shfl_xor(p, off, 64);
      float d = fmaf(-2.0f, p, a) + cemb[i];
      if (d < bd) { bd = d; bk = i; }   // ascending i: strict < keeps first
    }
  }

  // ---- fused gather + STE + loss (winner row L2-hot; zv already held) ----
  const float4 ev = *reinterpret_cast<const float4*>(
      emb + (size_t)bk * DDIM + lane * 4);
  float dx = ev.x - zv.x;                 // z_q - z (exact ref chain)
  float dy = ev.y - zv.y;
  float dz = ev.z - zv.z;
  float dw = ev.w - zv.w;
  float4 o = {zv.x + dx, zv.y + dy, zv.z + dz, zv.w + dw};  // z + (z_q - z)
  *reinterpret_cast<float4*>(out_zq + (size_t)row * DDIM + lane * 4) = o;
  float lsum = dx * dx;
  lsum = fmaf(dy, dy, lsum);
  lsum = fmaf(dz, dz, lsum);
  lsum = fmaf(dw, dw, lsum);
  #pragma unroll
  for (int off = 1; off < 64; off <<= 1) lsum += __shfl_xor(lsum, off, 64);
  if (lane == 0) {
    part4[wid] = lsum;
    out_idx[row] = (float)bk;
  }
  __syncthreads();
  if (threadIdx.x == 0) {
    float tot = (part4[0] + part4[1]) + (part4[2] + part4[3]);
    atomicAdd(&part[blockIdx.x & 255], (double)tot);
  }
}

__global__ void vq_finalize_fused(const double* __restrict__ part,
                                  float* __restrict__ out_losses) {
  int lane = threadIdx.x & 63;
  double s = part[lane] + part[lane + 64] + part[lane + 128] + part[lane + 192];
  #pragma unroll
  for (int off = 1; off < 64; off <<= 1) s += __shfl_xor(s, off, 64);
  if (lane == 0) {
    double m = s / (double)((size_t)NROWS * DDIM);
    out_losses[0] = (float)(0.25 * m);   // loss_commit = BETA * mse
    out_losses[1] = (float)m;            // loss_codebook
  }
}

// ---------------- R18 fallback path (small ws): separate kernels --------
__global__ __launch_bounds__(256)
void vq_rescore(const float* __restrict__ z, const float* __restrict__ emb,
                const float* __restrict__ arow, const float* __restrict__ cemb,
                const unsigned* __restrict__ cnt, const int* __restrict__ list,
                int* __restrict__ ws_idx) {
  const int row  = blockIdx.x * 4 + (threadIdx.x >> 6);
  const int lane = threadIdx.x & 63;
  const float a  = arow[row];
  const float4 zv = *reinterpret_cast<const float4*>(
      z + (size_t)row * DDIM + lane * 4);
  unsigned n = cnt[row];
  float bd = 3.4e38f;
  int   bk = 0;
  const bool fullscan = (n == 0 || n > CAP);
  const int  m = fullscan ? NE : (int)n;
  for (int i = 0; i < m; ++i) {
    int k = fullscan ? i : list[(size_t)row * CAP + i];
    const float4 ev = *reinterpret_cast<const float4*>(
        emb + (size_t)k * DDIM + lane * 4);
    float p = zv.x * ev.x;
    p = fmaf(zv.y, ev.y, p);
    p = fmaf(zv.z, ev.z, p);
    p = fmaf(zv.w, ev.w, p);
    #pragma unroll
    for (int off = 1; off < 64; off <<= 1) p += __shfl_xor(p, off, 64);
    float d = fmaf(-2.0f, p, a) + cemb[k];
    if (d < bd || (d == bd && k < bk)) { bd = d; bk = k; }
  }
  if (lane == 0) ws_idx[row] = bk;
}

__global__ __launch_bounds__(256)
void vq_gather(const float* __restrict__ z, const float* __restrict__ emb,
               const int* __restrict__ ws_idx,
               float* __restrict__ out_zq, float* __restrict__ out_idx,
               double* __restrict__ loss_accum) {
  __shared__ float part[4];
  const int t    = threadIdx.x;
  const int wid  = t >> 6;
  const int lane = t & 63;
  const int R0   = blockIdx.x * 64;
  float lsum = 0.0f;
  for (int rr = 0; rr < 16; ++rr) {
    const int row = R0 + rr * 4 + wid;
    const int kb  = ws_idx[row];
    const float4 zv = *reinterpret_cast<const float4*>(
        z + (size_t)row * DDIM + lane * 4);
    const float4 ev = *reinterpret_cast<const float4*>(
        emb + (size_t)kb * DDIM + lane * 4);
    float dx = ev.x - zv.x;
    float dy = ev.y - zv.y;
    float dz = ev.z - zv.z;
    float dw = ev.w - zv.w;
    float4 o = {zv.x + dx, zv.y + dy, zv.z + dz, zv.w + dw};
    *reinterpret_cast<float4*>(out_zq + (size_t)row * DDIM + lane * 4) = o;
    lsum = fmaf(dx, dx, lsum);
    lsum = fmaf(dy, dy, lsum);
    lsum = fmaf(dz, dz, lsum);
    lsum = fmaf(dw, dw, lsum);
  }
  #pragma unroll
  for (int off = 1; off < 64; off <<= 1) lsum += __shfl_xor(lsum, off, 64);
  if (lane == 0) part[wid] = lsum;
  __syncthreads();
  if (t == 0) {
    float tot = (part[0] + part[1]) + (part[2] + part[3]);
    atomicAdd(loss_accum, (double)tot);
  }
  if (t < 64) out_idx[R0 + t] = (float)ws_idx[R0 + t];
}

__global__ void vq_finalize(const double* __restrict__ loss_accum,
                            float* __restrict__ out_losses) {
  double m = *loss_accum / (double)((size_t)NROWS * DDIM);
  out_losses[0] = (float)(0.25 * m);
  out_losses[1] = (float)m;
}

extern "C" void kernel_launch(void* const* d_in, const int* in_sizes, int n_in,
                              void* d_out, int out_size, void* d_ws, size_t ws_size,
                              hipStream_t stream) {
  const float* z   = (const float*)d_in[0];
  const float* emb = (const float*)d_in[1];
  float* out        = (float*)d_out;
  float* out_zq     = out;                            // [8388608]
  float* out_losses = out + (size_t)NROWS * DDIM;     // [2]
  float* out_idx    = out + (size_t)NROWS * DDIM + 2; // [32768] as f32

  const bool big_ws = ws_size >= (size_t)(14u << 20);

  if (big_ws) {
    // ---- all scratch in d_ws; d_out never aliased => fused tail ----
    char* w = (char*)d_ws;
    double*   part = (double*)w;                      // [256] @ 0 (2KB)
    float*    arow = (float*)(w + 4096);              // 128KB
    float*    cemb = (float*)(w + 4096 + 131072);     // 32KB
    unsigned* cnt  = (unsigned*)(w + 4096 + 131072 + 32768);  // 128KB
    u16*      e16  = (u16*)(w + (1u << 20));          // 4MB @ 1MB
    int*      list = (int*)(w + (5u << 20));          // 8MB @ 5MB

    hipMemsetAsync(part, 0, 2048, stream);
    hipMemsetAsync(cnt, 0, NROWS * sizeof(unsigned), stream);
    vq_norms<<<(NROWS + NE) / 4, 256, 0, stream>>>(z, emb, arow, cemb);
    vq_cvt<<<NE * 32 / 256, 256, 0, stream>>>(emb, e16);
    vq_mfma<<<NROWS / BM, 512, 0, stream>>>(z, e16, arow, cemb, cnt, list);
    vq_rescore_fused<<<NROWS / 4, 256, 0, stream>>>(z, emb, arow, cemb,
                                                    cnt, list,
                                                    out_zq, out_idx, part);
    vq_finalize_fused<<<1, 64, 0, stream>>>(part, out_losses);
  } else {
    // ---- R18 fallback: scratch carved from d_out, separate kernels ----
    double* loss_accum = (double*)d_ws;
    float*  arow   = (float*)((char*)d_ws + 256);
    float*  cemb   = arow + NROWS;
    int*    ws_idx = (int*)(cemb + NE);

    u16*      e16  = (u16*)d_out;                            // [0, 4MB)
    int*      list = (int*)((char*)d_out + (4 << 20));       // [4MB, 12MB)
    unsigned* cnt  = (unsigned*)((char*)d_out + (12 << 20)); // [12MB, +128KB)

    hipMemsetAsync(d_ws, 0, 8, stream);
    hipMemsetAsync(cnt, 0, NROWS * sizeof(unsigned), stream);
    vq_norms<<<(NROWS + NE) / 4, 256, 0, stream>>>(z, emb, arow, cemb);
    vq_cvt<<<NE * 32 / 256, 256, 0, stream>>>(emb, e16);
    vq_mfma<<<NROWS / BM, 512, 0, stream>>>(z, e16, arow, cemb, cnt, list);
    vq_rescore<<<NROWS / 4, 256, 0, stream>>>(z, emb, arow, cemb, cnt, list,
                                              ws_idx);
    vq_gather<<<NROWS / 64, 256, 0, stream>>>(z, emb, ws_idx,
                                              out_zq, out_idx, loss_accum);
    vq_finalize<<<1, 1, 0, stream>>>(loss_accum, out_losses);
  }
}

// Round 24
// 271.687 us; speedup vs baseline: 1.7718x; 1.0892x over previous
//
#include <hip/hip_runtime.h>

// VectorQuantizer: bf16-MFMA approximate distance pass + margin shortlist +
// exact f32 rescore (+fused gather when scratch permits) + losses.
// N=32768, D=256, K=8192.
//
// R24 = R23 (296us best: T5 setprio banked) + ONE change: rescore_fused's
// shortlist scan parallelized 4x across 16-lane subgroups (candidate i ->
// subgroup i&3; lane holds 16 row elements; 16-fmaf local dot + 4-level
// shuffle reduce; cross-subgroup lex-(d,k) reduce -- order-independent vs
// the atomic-append list order, same first-index tie-break). R23's serial
// scan was 12 dependent (load + 6-shuffle-tree) iterations ~= 41us.
// p-summation order changes (same risk class as the rescore-vs-JAX order
// difference that has passed 18 rounds; gate: absmax 0, else revert).

#define NROWS 32768
#define NE    8192
#define DDIM  256
#define BM    64
#define CAP   64
#define MARGIN 1e-4f
#define NCH   (NE / 64)    // 128 chunks of 64 candidates

typedef __attribute__((ext_vector_type(8))) short bf16x8;
typedef __attribute__((ext_vector_type(4))) float f32x4;
typedef unsigned short u16;

__device__ __forceinline__ u16 f2bf(float f) {
  unsigned x = __float_as_uint(f);
  return (u16)((x + 0x7fffu + ((x >> 16) & 1u)) >> 16);   // RNE
}

__device__ __forceinline__ void gload_lds16(const void* g, void* l) {
  __builtin_amdgcn_global_load_lds(
      (const __attribute__((address_space(1))) void*)g,
      (__attribute__((address_space(3))) void*)l, 16, 0, 0);
}

// ---------------- row norms: a[n] = sum z^2, c[k] = sum e^2 -------------
__global__ __launch_bounds__(256)
void vq_norms(const float* __restrict__ z, const float* __restrict__ emb,
              float* __restrict__ arow, float* __restrict__ cemb) {
  int gid  = blockIdx.x * 256 + threadIdx.x;
  int wid  = gid >> 6;
  int lane = threadIdx.x & 63;
  const float* src;
  float* dst;
  if (wid < NROWS) { src = z + (size_t)wid * DDIM;   dst = arow + wid; }
  else             { int r = wid - NROWS;
                     src = emb + (size_t)r * DDIM;   dst = cemb + r; }
  float4 v = *reinterpret_cast<const float4*>(src + lane * 4);
  float s = v.x * v.x + v.y * v.y;
  s += v.z * v.z;
  s += v.w * v.w;
  #pragma unroll
  for (int off = 1; off < 64; off <<= 1) s += __shfl_xor(s, off, 64);
  if (lane == 0) *dst = s;
}

// -------- emb f32 -> bf16, FRAGMENT-MAJOR (R13..R18-verified) -----------
__global__ __launch_bounds__(256)
void vq_cvt(const float* __restrict__ emb, u16* __restrict__ e16) {
  int o   = blockIdx.x * 256 + threadIdx.x;   // 0 .. NE*32-1
  int g16 = o >> 9;
  int r   = o & 511;
  int s   = r >> 6;
  int l   = r & 63;
  int lg  = l >> 4, l15 = l & 15;
  int c   = g16 * 16 + l15;
  int kc  = s * 4 + lg;
  const float* src = emb + (size_t)c * DDIM + kc * 8;
  float4 v0 = *reinterpret_cast<const float4*>(src);
  float4 v1 = *reinterpret_cast<const float4*>(src + 4);
  u16 ov[8] = {f2bf(v0.x), f2bf(v0.y), f2bf(v0.z), f2bf(v0.w),
               f2bf(v1.x), f2bf(v1.y), f2bf(v1.z), f2bf(v1.w)};
  *reinterpret_cast<bf16x8*>(e16 + (size_t)o * 8) =
      *reinterpret_cast<bf16x8*>(ov);
}

// ---------------- MFMA approx pass + shortlist (R23 verbatim) -----------
__global__ __launch_bounds__(512, 4)
void vq_mfma(const float* __restrict__ z, const u16* __restrict__ e16,
             const float* __restrict__ arow, const float* __restrict__ cemb,
             unsigned* __restrict__ cnt, int* __restrict__ list) {
  __shared__ u16 Bs[2][64 * DDIM];   // 2 x 32 KB, fragment-major

  const int t    = threadIdx.x;
  const int R0   = blockIdx.x * BM;
  const int lane = t & 63;
  const int wid  = t >> 6;          // 0..7
  const int wm   = wid >> 1;        // 0..3 : 16-row group
  const int wn   = wid & 1;         // 0..1 : 32-cand half
  const int l15  = lane & 15;
  const int lg   = lane >> 4;       // 0..3

  bf16x8 af[8];
  const int row = R0 + wm * 16 + l15;
  {
    const float* zr = z + (size_t)row * DDIM;
    #pragma unroll
    for (int s = 0; s < 8; ++s) {
      const float* src = zr + (s * 4 + lg) * 8;
      float4 v0 = *reinterpret_cast<const float4*>(src);
      float4 v1 = *reinterpret_cast<const float4*>(src + 4);
      u16 o[8] = {f2bf(v0.x), f2bf(v0.y), f2bf(v0.z), f2bf(v0.w),
                  f2bf(v1.x), f2bf(v1.y), f2bf(v1.z), f2bf(v1.w)};
      af[s] = *reinterpret_cast<bf16x8*>(o);
    }
  }
  const float a_r = arow[row];
  float runmin = 3.4e38f;

  {
    const char* src = (const char*)e16;
    #pragma unroll
    for (int i = 0; i < 4; ++i) {
      int f = wid * 4 + i;
      gload_lds16(src + f * 1024 + lane * 16, (char*)&Bs[0][0] + f * 1024);
    }
  }
  __syncthreads();   // drains prologue DMA

  for (int ch = 0; ch < NCH; ++ch) {
    const int buf = ch & 1;
    const int C0  = ch * 64;

    if (ch + 1 < NCH) {
      const char* src = (const char*)e16 + (size_t)(ch + 1) * 32768;
      char* dst = (char*)&Bs[buf ^ 1][0];
      #pragma unroll
      for (int i = 0; i < 4; ++i) {
        int f = wid * 4 + i;
        gload_lds16(src + f * 1024 + lane * 16, dst + f * 1024);
      }
    }

    float4 cvv[2];
    #pragma unroll
    for (int ci = 0; ci < 2; ++ci)
      cvv[ci] = *reinterpret_cast<const float4*>(
          &cemb[C0 + wn * 32 + ci * 16 + lg * 4]);

    f32x4 acc[2];
    acc[0] = (f32x4){0.f, 0.f, 0.f, 0.f};
    acc[1] = (f32x4){0.f, 0.f, 0.f, 0.f};

    // ---- T5: priority-boost the MFMA cluster (2 blk/CU are desynced) ----
    __builtin_amdgcn_s_setprio(1);
    const u16* Bp = &Bs[buf][0];
    #pragma unroll
    for (int s = 0; s < 8; ++s) {
      bf16x8 bfr[2];
      #pragma unroll
      for (int ci = 0; ci < 2; ++ci)
        bfr[ci] = *reinterpret_cast<const bf16x8*>(
            &Bp[((wn * 2 + ci) * 8 + s) * 512 + lane * 8]);
      #pragma unroll
      for (int ci = 0; ci < 2; ++ci)
        acc[ci] = __builtin_amdgcn_mfma_f32_16x16x32_bf16(
            bfr[ci], af[s], acc[ci], 0, 0, 0);
    }
    __builtin_amdgcn_s_setprio(0);

    __syncthreads();   // compute(buf) done by ALL waves; next DMA drained

    // ---- POST-BARRIER epilogue (regs + global only, no LDS) ----
    float lm = 3.4e38f;
    #pragma unroll
    for (int ci = 0; ci < 2; ++ci)
      #pragma unroll
      for (int r = 0; r < 4; ++r) {
        float dd = fmaf(-2.0f, acc[ci][r], a_r) + cvv[ci][r];
        lm = fminf(lm, dd);
      }
    float gm = fminf(lm, __shfl_xor(lm, 16, 64));
    gm = fminf(gm, __shfl_xor(gm, 32, 64));
    runmin = fminf(runmin, gm);
    float thr = runmin + MARGIN;
    if (lm <= thr) {
      // u-form test (R5-verified): d<=thr <=> u >= 0.5*(a+c-thr)
      const float h = 0.5f * (a_r - thr);
      #pragma unroll
      for (int ci = 0; ci < 2; ++ci)
        #pragma unroll
        for (int r = 0; r < 4; ++r)
          if (acc[ci][r] >= fmaf(0.5f, cvv[ci][r], h)) {
            int k = C0 + wn * 32 + ci * 16 + lg * 4 + r;
            unsigned p = atomicAdd(&cnt[row], 1u);
            if (p < CAP) list[(size_t)row * CAP + p] = k;
          }
    }
  }
}

// -------- FUSED exact rescore + gather + STE + loss (big-ws path) -------
// Shortlist scan parallelized: candidate i -> subgroup i&3 (16 lanes);
// lane holds 16 row elements; cross-subgroup lex-(d,k) reduce.
__global__ __launch_bounds__(256)
void vq_rescore_fused(const float* __restrict__ z, const float* __restrict__ emb,
                      const float* __restrict__ arow, const float* __restrict__ cemb,
                      const unsigned* __restrict__ cnt, const int* __restrict__ list,
                      float* __restrict__ out_zq, float* __restrict__ out_idx,
                      double* __restrict__ part) {
  __shared__ float part4[4];
  const int wid  = threadIdx.x >> 6;
  const int row  = blockIdx.x * 4 + wid;
  const int lane = threadIdx.x & 63;
  const float a  = arow[row];
  unsigned n = cnt[row];
  float bd = 3.4e38f;
  int   bk = 0;

  if (n != 0 && n <= CAP) {
    // parallel shortlist scan: 4 candidates in flight (16-lane subgroups)
    const int sg  = lane >> 4;
    const int l15 = lane & 15;
    float4 zq[4];
    #pragma unroll
    for (int q = 0; q < 4; ++q)
      zq[q] = *reinterpret_cast<const float4*>(
          z + (size_t)row * DDIM + l15 * 16 + q * 4);
    for (int i = sg; i < (int)n; i += 4) {
      int k = list[(size_t)row * CAP + i];
      const float* ep = emb + (size_t)k * DDIM + l15 * 16;
      float p = 0.0f;
      #pragma unroll
      for (int q = 0; q < 4; ++q) {
        const float4 ev = *reinterpret_cast<const float4*>(ep + q * 4);
        p = fmaf(zq[q].x, ev.x, p);
        p = fmaf(zq[q].y, ev.y, p);
        p = fmaf(zq[q].z, ev.z, p);
        p = fmaf(zq[q].w, ev.w, p);
      }
      p += __shfl_xor(p, 1, 64);
      p += __shfl_xor(p, 2, 64);
      p += __shfl_xor(p, 4, 64);
      p += __shfl_xor(p, 8, 64);
      float d = fmaf(-2.0f, p, a) + cemb[k];   // exact ref chain
      if (d < bd || (d == bd && k < bk)) { bd = d; bk = k; }
    }
    // cross-subgroup lexicographic (d, k) reduce -> all 64 lanes hold winner
    #pragma unroll
    for (int off = 16; off < 64; off <<= 1) {
      float od = __shfl_xor(bd, off, 64);
      int   ok = __shfl_xor(bk, off, 64);
      if (od < bd || (od == bd && ok < bk)) { bd = od; bk = ok; }
    }
  } else {
    // overflow fallback (statistically never): serial full scan (R22-verified)
    const float4 zv = *reinterpret_cast<const float4*>(
        z + (size_t)row * DDIM + lane * 4);
    for (int i = 0; i < NE; ++i) {
      const float4 ev = *reinterpret_cast<const float4*>(
          emb + (size_t)i * DDIM + lane * 4);
      float p = zv.x * ev.x;
      p = fmaf(zv.y, ev.y, p);
      p = fmaf(zv.z, ev.z, p);
      p = fmaf(zv.w, ev.w, p);
      #pragma unroll
      for (int off = 1; off < 64; off <<= 1) p += __shfl_xor(p, off, 64);
      float d = fmaf(-2.0f, p, a) + cemb[i];
      if (d < bd) { bd = d; bk = i; }   // ascending i: strict < keeps first
    }
  }

  // ---- fused gather + STE + loss (winner + z rows L2-hot) ----
  const float4 zv = *reinterpret_cast<const float4*>(
      z + (size_t)row * DDIM + lane * 4);
  const float4 ev = *reinterpret_cast<const float4*>(
      emb + (size_t)bk * DDIM + lane * 4);
  float dx = ev.x - zv.x;                 // z_q - z (exact ref chain)
  float dy = ev.y - zv.y;
  float dz = ev.z - zv.z;
  float dw = ev.w - zv.w;
  float4 o = {zv.x + dx, zv.y + dy, zv.z + dz, zv.w + dw};  // z + (z_q - z)
  *reinterpret_cast<float4*>(out_zq + (size_t)row * DDIM + lane * 4) = o;
  float lsum = dx * dx;
  lsum = fmaf(dy, dy, lsum);
  lsum = fmaf(dz, dz, lsum);
  lsum = fmaf(dw, dw, lsum);
  #pragma unroll
  for (int off = 1; off < 64; off <<= 1) lsum += __shfl_xor(lsum, off, 64);
  if (lane == 0) {
    part4[wid] = lsum;
    out_idx[row] = (float)bk;
  }
  __syncthreads();
  if (threadIdx.x == 0) {
    float tot = (part4[0] + part4[1]) + (part4[2] + part4[3]);
    atomicAdd(&part[blockIdx.x & 255], (double)tot);
  }
}

__global__ void vq_finalize_fused(const double* __restrict__ part,
                                  float* __restrict__ out_losses) {
  int lane = threadIdx.x & 63;
  double s = part[lane] + part[lane + 64] + part[lane + 128] + part[lane + 192];
  #pragma unroll
  for (int off = 1; off < 64; off <<= 1) s += __shfl_xor(s, off, 64);
  if (lane == 0) {
    double m = s / (double)((size_t)NROWS * DDIM);
    out_losses[0] = (float)(0.25 * m);   // loss_commit = BETA * mse
    out_losses[1] = (float)m;            // loss_codebook
  }
}

// ---------------- R18 fallback path (small ws): separate kernels --------
__global__ __launch_bounds__(256)
void vq_rescore(const float* __restrict__ z, const float* __restrict__ emb,
                const float* __restrict__ arow, const float* __restrict__ cemb,
                const unsigned* __restrict__ cnt, const int* __restrict__ list,
                int* __restrict__ ws_idx) {
  const int row  = blockIdx.x * 4 + (threadIdx.x >> 6);
  const int lane = threadIdx.x & 63;
  const float a  = arow[row];
  const float4 zv = *reinterpret_cast<const float4*>(
      z + (size_t)row * DDIM + lane * 4);
  unsigned n = cnt[row];
  float bd = 3.4e38f;
  int   bk = 0;
  const bool fullscan = (n == 0 || n > CAP);
  const int  m = fullscan ? NE : (int)n;
  for (int i = 0; i < m; ++i) {
    int k = fullscan ? i : list[(size_t)row * CAP + i];
    const float4 ev = *reinterpret_cast<const float4*>(
        emb + (size_t)k * DDIM + lane * 4);
    float p = zv.x * ev.x;
    p = fmaf(zv.y, ev.y, p);
    p = fmaf(zv.z, ev.z, p);
    p = fmaf(zv.w, ev.w, p);
    #pragma unroll
    for (int off = 1; off < 64; off <<= 1) p += __shfl_xor(p, off, 64);
    float d = fmaf(-2.0f, p, a) + cemb[k];
    if (d < bd || (d == bd && k < bk)) { bd = d; bk = k; }
  }
  if (lane == 0) ws_idx[row] = bk;
}

__global__ __launch_bounds__(256)
void vq_gather(const float* __restrict__ z, const float* __restrict__ emb,
               const int* __restrict__ ws_idx,
               float* __restrict__ out_zq, float* __restrict__ out_idx,
               double* __restrict__ loss_accum) {
  __shared__ float part[4];
  const int t    = threadIdx.x;
  const int wid  = t >> 6;
  const int lane = t & 63;
  const int R0   = blockIdx.x * 64;
  float lsum = 0.0f;
  for (int rr = 0; rr < 16; ++rr) {
    const int row = R0 + rr * 4 + wid;
    const int kb  = ws_idx[row];
    const float4 zv = *reinterpret_cast<const float4*>(
        z + (size_t)row * DDIM + lane * 4);
    const float4 ev = *reinterpret_cast<const float4*>(
        emb + (size_t)kb * DDIM + lane * 4);
    float dx = ev.x - zv.x;
    float dy = ev.y - zv.y;
    float dz = ev.z - zv.z;
    float dw = ev.w - zv.w;
    float4 o = {zv.x + dx, zv.y + dy, zv.z + dz, zv.w + dw};
    *reinterpret_cast<float4*>(out_zq + (size_t)row * DDIM + lane * 4) = o;
    lsum = fmaf(dx, dx, lsum);
    lsum = fmaf(dy, dy, lsum);
    lsum = fmaf(dz, dz, lsum);
    lsum = fmaf(dw, dw, lsum);
  }
  #pragma unroll
  for (int off = 1; off < 64; off <<= 1) lsum += __shfl_xor(lsum, off, 64);
  if (lane == 0) part[wid] = lsum;
  __syncthreads();
  if (t == 0) {
    float tot = (part[0] + part[1]) + (part[2] + part[3]);
    atomicAdd(loss_accum, (double)tot);
  }
  if (t < 64) out_idx[R0 + t] = (float)ws_idx[R0 + t];
}

__global__ void vq_finalize(const double* __restrict__ loss_accum,
                            float* __restrict__ out_losses) {
  double m = *loss_accum / (double)((size_t)NROWS * DDIM);
  out_losses[0] = (float)(0.25 * m);
  out_losses[1] = (float)m;
}

extern "C" void kernel_launch(void* const* d_in, const int* in_sizes, int n_in,
                              void* d_out, int out_size, void* d_ws, size_t ws_size,
                              hipStream_t stream) {
  const float* z   = (const float*)d_in[0];
  const float* emb = (const float*)d_in[1];
  float* out        = (float*)d_out;
  float* out_zq     = out;                            // [8388608]
  float* out_losses = out + (size_t)NROWS * DDIM;     // [2]
  float* out_idx    = out + (size_t)NROWS * DDIM + 2; // [32768] as f32

  const bool big_ws = ws_size >= (size_t)(14u << 20);

  if (big_ws) {
    // ---- all scratch in d_ws; d_out never aliased => fused tail ----
    char* w = (char*)d_ws;
    double*   part = (double*)w;                      // [256] @ 0 (2KB)
    float*    arow = (float*)(w + 4096);              // 128KB
    float*    cemb = (float*)(w + 4096 + 131072);     // 32KB
    unsigned* cnt  = (unsigned*)(w + 4096 + 131072 + 32768);  // 128KB
    u16*      e16  = (u16*)(w + (1u << 20));          // 4MB @ 1MB
    int*      list = (int*)(w + (5u << 20));          // 8MB @ 5MB

    hipMemsetAsync(part, 0, 2048, stream);
    hipMemsetAsync(cnt, 0, NROWS * sizeof(unsigned), stream);
    vq_norms<<<(NROWS + NE) / 4, 256, 0, stream>>>(z, emb, arow, cemb);
    vq_cvt<<<NE * 32 / 256, 256, 0, stream>>>(emb, e16);
    vq_mfma<<<NROWS / BM, 512, 0, stream>>>(z, e16, arow, cemb, cnt, list);
    vq_rescore_fused<<<NROWS / 4, 256, 0, stream>>>(z, emb, arow, cemb,
                                                    cnt, list,
                                                    out_zq, out_idx, part);
    vq_finalize_fused<<<1, 64, 0, stream>>>(part, out_losses);
  } else {
    // ---- R18 fallback: scratch carved from d_out, separate kernels ----
    double* loss_accum = (double*)d_ws;
    float*  arow   = (float*)((char*)d_ws + 256);
    float*  cemb   = arow + NROWS;
    int*    ws_idx = (int*)(cemb + NE);

    u16*      e16  = (u16*)d_out;                            // [0, 4MB)
    int*      list = (int*)((char*)d_out + (4 << 20));       // [4MB, 12MB)
    unsigned* cnt  = (unsigned*)((char*)d_out + (12 << 20)); // [12MB, +128KB)

    hipMemsetAsync(d_ws, 0, 8, stream);
    hipMemsetAsync(cnt, 0, NROWS * sizeof(unsigned), stream);
    vq_norms<<<(NROWS + NE) / 4, 256, 0, stream>>>(z, emb, arow, cemb);
    vq_cvt<<<NE * 32 / 256, 256, 0, stream>>>(emb, e16);
    vq_mfma<<<NROWS / BM, 512, 0, stream>>>(z, e16, arow, cemb, cnt, list);
    vq_rescore<<<NROWS / 4, 256, 0, stream>>>(z, emb, arow, cemb, cnt, list,
                                              ws_idx);
    vq_gather<<<NROWS / 64, 256, 0, stream>>>(z, emb, ws_idx,
                                              out_zq, out_idx, loss_accum);
    vq_finalize<<<1, 1, 0, stream>>>(loss_accum, out_losses);
  }
}